// Round 10
// baseline (168.248 us; speedup 1.0000x reference)
//
#include <hip/hip_runtime.h>
#include <cfloat>

// Problem constants: inputs (64,256,512) fp32, emb (1024,512) fp32.
#define NROWS  16384          // 64*256
#define DIM    512
#define KC     1024
#define QELEMS (NROWS * DIM)  // 8388608
// d_out layout (fp32): [0]=loss, [1 .. QELEMS]=quantized, [1+QELEMS .. +NROWS]=indices (as float)

#define NSPLIT 8              // one per 128-code column block
#define CHUNKS 130            // kq-plane stride in 16B chunks: 130 -> write bank
                              // (skq*8+srow*4)%32 and read bank (qd*8+tx*4)%32,
                              // both distinct within every 8-lane phase = conflict-free

typedef float  floatx4 __attribute__((ext_vector_type(4)));
typedef _Float16 half8 __attribute__((ext_vector_type(8)));
typedef _Float16 half4 __attribute__((ext_vector_type(4)));

// ---------------- kernel 1: fused prep (A and E) ----------------
// blocks [0,4096): A rows; [4096,4352): E rows. rowsq tree + split math VERBATIM
// from the passing rounds (part of the verified rounding structure).
__global__ __launch_bounds__(256) void prep_kernel(const float* __restrict__ A,
                                                   const float* __restrict__ E,
                                                   float* __restrict__ xsq,
                                                   float* __restrict__ esq,
                                                   _Float16* __restrict__ ah,
                                                   _Float16* __restrict__ al,
                                                   _Float16* __restrict__ eh,
                                                   _Float16* __restrict__ el,
                                                   unsigned long long* __restrict__ packed,
                                                   float* __restrict__ out) {
    if (blockIdx.x == 0 && threadIdx.x == 0) out[0] = 0.f;
    const int wave = threadIdx.x >> 6, lane = threadIdx.x & 63;
    const bool isA = blockIdx.x < (NROWS / 4);
    const int row = (isA ? blockIdx.x : blockIdx.x - NROWS / 4) * 4 + wave;
    const float* M = isA ? A : E;
    const float scale = isA ? 2048.0f : 65536.0f;

    const float4* Mr = (const float4*)(M + (size_t)row * DIM);
    float4 va = Mr[lane];
    float4 vb = Mr[lane + 64];
    float s = 0.f;
    s += va.x*va.x + va.y*va.y + va.z*va.z + va.w*va.w;   // same tree as rowsq i=0
    s += vb.x*vb.x + vb.y*vb.y + vb.z*vb.z + vb.w*vb.w;   // i=1
    #pragma unroll
    for (int off = 32; off; off >>= 1) s += __shfl_down(s, off, 64);
    if (lane == 0) {
        if (isA) { xsq[row] = s; packed[row] = ~0ULL; }
        else     { esq[row] = s; }
    }

    float xa[4] = {va.x, va.y, va.z, va.w}, xb[4] = {vb.x, vb.y, vb.z, vb.w};
    half4 ha, la, hb, lb;
    #pragma unroll
    for (int e = 0; e < 4; ++e) {
        float t = xa[e] * scale;
        _Float16 h = (_Float16)t;
        ha[e] = h; la[e] = (_Float16)(t - (float)h);
        t = xb[e] * scale;
        h = (_Float16)t;
        hb[e] = h; lb[e] = (_Float16)(t - (float)h);
    }
    _Float16* hr = (isA ? ah : eh) + (size_t)row * DIM;
    _Float16* lr = (isA ? al : el) + (size_t)row * DIM;
    ((half4*)hr)[lane]      = ha;
    ((half4*)lr)[lane]      = la;
    ((half4*)hr)[lane + 64] = hb;
    ((half4*)lr)[lane + 64] = lb;
}

// ---------------- kernel 2: MFMA distance GEMM + fused argmin ----------------
// Round-10 structure: SINGLE-buffered LDS holding only A-hi, E-hi, E-lo
// (~25 KB -> 4-5 blocks/CU; round 9's 68 KB double-buffer capped at 2 and
// the 900-cyc/interval barrier slack had nothing to hide behind). A-lo
// fragments stream global->VGPR directly (fragment pattern is globally
// addressable; needed only at MFMA phase 3 -> long latency slack; L2-hot
// via the XCD swizzle). CHUNKS=130 makes BOTH ds_write and ds_read phases
// bank-conflict-free (round 9's 132 cost 8.4M conflict cycles on writes).
// MFMA inputs and accumulation order VERBATIM -> acc bit-identical.
// Score keeps the PASSING rounding structure: s = fl( fl(sqx+sqe) - acc*2^-26 ).
__global__ __launch_bounds__(256) void mfma_argmin_kernel(const _Float16* __restrict__ ah,
                                                          const _Float16* __restrict__ al,
                                                          const _Float16* __restrict__ eh,
                                                          const _Float16* __restrict__ el,
                                                          const float* __restrict__ esq,
                                                          const float* __restrict__ xsq,
                                                          unsigned long long* __restrict__ packed) {
    __shared__ half8 AhT[4 * CHUNKS], EhT[4 * CHUNKS], ElT[4 * CHUNKS];
    __shared__ float redv[128][2];
    __shared__ int   redi[128][2];

    const int tid = threadIdx.x;
    const int lane = tid & 63, wave = tid >> 6;
    const int wm = wave >> 1, wn = wave & 1;      // 2x2 wave grid
    const int tx = lane & 15, qd = lane >> 4;
    const int bm = blockIdx.x & 127, bn = blockIdx.x >> 7;   // XCD-aware swizzle
    const int m0 = bm * 128, c0 = bn * 128;

    // staging: thread t handles rows (t>>2), (t>>2)+64, k-chunk skq=t&3
    const int srow = tid >> 2, skq = tid & 3;
    const _Float16* gA  = ah + (size_t)(m0 + srow) * DIM + skq * 8;
    const _Float16* gE  = eh + (size_t)(c0 + srow) * DIM + skq * 8;
    const _Float16* gEl = el + (size_t)(c0 + srow) * DIM + skq * 8;
    const int cw0 = skq * CHUNKS + srow, cw1 = cw0 + 64;

    // A-lo fragment base: lane (tx,qd) of wave wm reads rows wm*64+i*16+tx
    const _Float16* gAl = al + (size_t)(m0 + wm * 64 + tx) * DIM + qd * 8;

    floatx4 acc[4][4];
    #pragma unroll
    for (int i = 0; i < 4; ++i)
        #pragma unroll
        for (int j = 0; j < 4; ++j) acc[i][j] = (floatx4){0.f, 0.f, 0.f, 0.f};

    #pragma unroll 1                               // spill guard: do not unroll K-loop
    for (int kt = 0; kt < DIM / 32; ++kt) {
        const int kb = kt * 32;
        // global loads issued first (latency overlapped with barrier + LDS phase)
        half8 sA0 = *(const half8*)(gA  + kb);
        half8 sA1 = *(const half8*)(gA  + 64 * DIM + kb);
        half8 sE0 = *(const half8*)(gE  + kb);
        half8 sE1 = *(const half8*)(gE  + 64 * DIM + kb);
        half8 sF0 = *(const half8*)(gEl + kb);
        half8 sF1 = *(const half8*)(gEl + 64 * DIM + kb);
        half8 fal[4];                              // A-lo fragments, direct from global
        #pragma unroll
        for (int i = 0; i < 4; ++i)
            fal[i] = *(const half8*)(gAl + (size_t)(i * 16) * DIM + kb);

        __syncthreads();                           // previous iteration's reads done
        AhT[cw0] = sA0; AhT[cw1] = sA1;
        EhT[cw0] = sE0; EhT[cw1] = sE1;
        ElT[cw0] = sF0; ElT[cw1] = sF1;
        __syncthreads();                           // writes visible

        half8 fa[4], fbh[4], fbl[4];
        #pragma unroll
        for (int i = 0; i < 4; ++i)
            fa[i] = AhT[qd * CHUNKS + wm * 64 + i * 16 + tx];
        #pragma unroll
        for (int j = 0; j < 4; ++j) {
            fbh[j] = EhT[qd * CHUNKS + wn * 64 + j * 16 + tx];
            fbl[j] = ElT[qd * CHUNKS + wn * 64 + j * 16 + tx];
        }
        #pragma unroll
        for (int i = 0; i < 4; ++i)
            #pragma unroll
            for (int j = 0; j < 4; ++j)
                acc[i][j] = __builtin_amdgcn_mfma_f32_16x16x32_f16(fa[i], fbh[j], acc[i][j], 0, 0, 0);
        #pragma unroll
        for (int i = 0; i < 4; ++i)
            #pragma unroll
            for (int j = 0; j < 4; ++j)
                acc[i][j] = __builtin_amdgcn_mfma_f32_16x16x32_f16(fa[i], fbl[j], acc[i][j], 0, 0, 0);
        #pragma unroll
        for (int i = 0; i < 4; ++i)
            #pragma unroll
            for (int j = 0; j < 4; ++j)
                acc[i][j] = __builtin_amdgcn_mfma_f32_16x16x32_f16(fal[i], fbh[j], acc[i][j], 0, 0, 0);
    }

    // ---- epilogue: scores + argmin (identical arithmetic to passing rounds) ----
    float sqe_v[4];
    #pragma unroll
    for (int j = 0; j < 4; ++j) sqe_v[j] = esq[c0 + wn * 64 + j * 16 + tx];
    #pragma unroll
    for (int i = 0; i < 4; ++i) {
        #pragma unroll
        for (int r = 0; r < 4; ++r) {
            int rl = wm * 64 + i * 16 + qd * 4 + r;        // C/D: row = qd*4+reg
            float sx = xsq[m0 + rl];
            float bvv = FLT_MAX; int bii = 0x7fffffff;
            #pragma unroll
            for (int j = 0; j < 4; ++j) {
                float S = sx + sqe_v[j];                   // fl(sqx + sqe)
                float s = S - acc[i][j][r] * (1.0f / 67108864.0f);  // fl(S - 2m)
                int c = c0 + wn * 64 + j * 16 + tx;
                if (s < bvv || (s == bvv && c < bii)) { bvv = s; bii = c; }
            }
            #pragma unroll
            for (int md = 1; md < 16; md <<= 1) {
                float ov = __shfl_xor(bvv, md, 64);
                int   oc = __shfl_xor(bii, md, 64);
                if (ov < bvv || (ov == bvv && oc < bii)) { bvv = ov; bii = oc; }
            }
            if (tx == 0) { redv[rl][wn] = bvv; redi[rl][wn] = bii; }
        }
    }
    __syncthreads();
    if (tid < 128) {
        float v0 = redv[tid][0], v1 = redv[tid][1];
        int   i0 = redi[tid][0], i1 = redi[tid][1];
        float v = (v1 < v0) ? v1 : v0;            // tie -> wn0 (smaller col)
        int   ix = (v1 < v0) ? i1 : i0;
        // scores positive -> float bits monotonic; lexicographic (bits,idx) min
        // == np.argmin first-occurrence tie-break.
        unsigned long long pk = ((unsigned long long)__float_as_uint(v) << 32)
                              | (unsigned int)ix;
        atomicMin(&packed[m0 + tid], pk);
    }
}

// ---------------- kernel 3: indices + gather quantized + loss from scores ----------------
// loss = 1.25 * mean(min-score): min score IS fl(||x-e||^2) to ~1e-4/row;
// summed error ~1e-7 << the 20.48 output threshold (passed round 9).
__global__ __launch_bounds__(256) void finalize_kernel(const float* __restrict__ E,
                                                       const unsigned long long* __restrict__ packed,
                                                       float* __restrict__ out) {
    float* q = out + 1;
    float* idxF = out + 1 + QELEMS;
    const int tid = threadIdx.x;
    const int r0 = blockIdx.x * 64;

    __shared__ int sidx[64];
    if (tid < 64) {                               // wave 0: unpack idx + score
        unsigned long long pk = packed[r0 + tid];
        int idx = (int)(unsigned int)(pk & 0xFFFFFFFFull);
        float sc = __uint_as_float((unsigned int)(pk >> 32));
        sidx[tid] = idx;
        idxF[r0 + tid] = (float)idx;
        #pragma unroll
        for (int off = 32; off; off >>= 1) sc += __shfl_down(sc, off, 64);
        if (tid == 0) atomicAdd(out, sc * (1.25f / (float)QELEMS));
    }
    __syncthreads();

    #pragma unroll 4
    for (int it = 0; it < 32; ++it) {             // 64 rows * 128 float4 = 8192 slots
        int flat = it * 256 + tid;
        int row = flat >> 7;
        int d4  = (flat & 127) * 4;
        int idx = sidx[row];
        float4 e = *(const float4*)(E + (size_t)idx * DIM + d4);
        *(float4*)(q + (size_t)(r0 + row) * DIM + d4) = e;
    }
}

extern "C" void kernel_launch(void* const* d_in, const int* in_sizes, int n_in,
                              void* d_out, int out_size, void* d_ws, size_t ws_size,
                              hipStream_t stream) {
    const float* A = (const float*)d_in[0];   // inputs (64,256,512)
    const float* E = (const float*)d_in[1];   // emb_weight (1024,512)
    float* out = (float*)d_out;

    unsigned long long* packed = (unsigned long long*)d_ws;     // 16384 u64
    float*    esq  = (float*)(packed + NROWS);                  // 1024
    float*    xsq  = esq + KC;                                  // 16384
    _Float16* eh   = (_Float16*)(xsq + NROWS);                  // 1024*512 (16B-aligned)
    _Float16* el   = eh + (size_t)KC * DIM;
    _Float16* ah   = el + (size_t)KC * DIM;                     // 16384*512
    _Float16* al   = ah + (size_t)NROWS * DIM;

    prep_kernel<<<NROWS / 4 + KC / 4, 256, 0, stream>>>(A, E, xsq, esq, ah, al, eh, el, packed, out);
    mfma_argmin_kernel<<<(NROWS / 128) * NSPLIT, 256, 0, stream>>>(
        ah, al, eh, el, esq, xsq, packed);
    finalize_kernel<<<NROWS / 64, 256, 0, stream>>>(E, packed, out);
}